// Round 4
// baseline (824.175 us; speedup 1.0000x reference)
//
#include <hip/hip_runtime.h>
#include <hip/hip_bf16.h>

// Problem constants (fixed by the reference)
#define HD   4096      // hidden
#define ID   14336     // intermediate
#define NB   64        // batch
#define NLUTN 4096
#define GU_KS 4        // gate/up cross-block K split (K chunk = 1024)
#define D_KS  16       // down cross-block K split   (K chunk = 896)

typedef __attribute__((ext_vector_type(8))) short short8;   // 8 x bf16 bits
typedef __attribute__((ext_vector_type(4))) float f32x4;    // MFMA accumulator

__device__ __forceinline__ unsigned short f2bf(float f) {
  __hip_bfloat16 h = __float2bfloat16(f);
  return __builtin_bit_cast(unsigned short, h);
}

// ---------------------------------------------------------------------------
// prep: x'_g[b][h] = bf16(x[b][h]*gsr[h]), x'_u likewise. [b][k] row-major.
// ---------------------------------------------------------------------------
__global__ __launch_bounds__(256) void prep_kernel(
    const float* __restrict__ x, const float* __restrict__ gsr,
    const float* __restrict__ usr,
    unsigned short* __restrict__ xg, unsigned short* __restrict__ xu)
{
  int t = blockIdx.x * 256 + threadIdx.x;          // 0..65535 float4s
  float4 xv = ((const float4*)x)[t];
  int hs = t & (HD/4 - 1);
  float4 g = ((const float4*)gsr)[hs];
  float4 u = ((const float4*)usr)[hs];
  ((ushort4*)xg)[t] = make_ushort4(f2bf(xv.x*g.x), f2bf(xv.y*g.y), f2bf(xv.z*g.z), f2bf(xv.w*g.w));
  ((ushort4*)xu)[t] = make_ushort4(f2bf(xv.x*u.x), f2bf(xv.y*u.y), f2bf(xv.z*u.z), f2bf(xv.w*u.w));
}

// ---------------------------------------------------------------------------
// gate+up: block = 4 waves, wave w owns I-rows 16w..16w+15 of a 64-row strip.
// K chunk = 1024, grid (ID/64, GU_KS) = (224, 4).
// NO barriers in the K-loop: B frags are per-lane global loads (xg/xu are L2-
// resident, 1 MB total), walks are per-lane int4 loads; both 1-iter register-
// prefetched so the compiler emits fine-grained vmcnt waits and each wave
// keeps ~12 vmem ops in flight. LDS = LUTs only (16 KB).
// f32 atomicAdd partials into pg/pu.
// ---------------------------------------------------------------------------
__global__ __launch_bounds__(256, 4) void gate_up_kernel(
    const int* __restrict__ gw, const int* __restrict__ uw,
    const float* __restrict__ lutg_f, const float* __restrict__ lutu_f,
    const unsigned short* __restrict__ xg, const unsigned short* __restrict__ xu,
    float* __restrict__ pg, float* __restrict__ pu)
{
  __shared__ unsigned short lutg[NLUTN];       // 8 KB
  __shared__ unsigned short lutu[NLUTN];       // 8 KB

  const int tid = threadIdx.x;
  #pragma unroll
  for (int i = tid; i < NLUTN/4; i += 256) {
    float4 g = ((const float4*)lutg_f)[i];
    float4 u = ((const float4*)lutu_f)[i];
    ((ushort4*)lutg)[i] = make_ushort4(f2bf(g.x), f2bf(g.y), f2bf(g.z), f2bf(g.w));
    ((ushort4*)lutu)[i] = make_ushort4(f2bf(u.x), f2bf(u.y), f2bf(u.z), f2bf(u.w));
  }
  __syncthreads();   // the ONLY barrier

  const int lane = tid & 63;
  const int wv   = tid >> 6;
  const int col  = lane & 15;
  const int quad = lane >> 4;
  const int m0   = blockIdx.x * 64;
  const int mrow0 = m0 + wv * 16;
  const int kb   = blockIdx.y * (HD / GU_KS);
  const int KC   = HD / GU_KS;                 // 1024

  const int* gp = gw + (size_t)(mrow0 + col) * HD + kb + quad * 8;
  const int* up = uw + (size_t)(mrow0 + col) * HD + kb + quad * 8;
  const unsigned short* xgp[4];
  const unsigned short* xup[4];
  #pragma unroll
  for (int t = 0; t < 4; ++t) {
    xgp[t] = xg + (size_t)(t*16 + col) * HD + kb + quad * 8;
    xup[t] = xu + (size_t)(t*16 + col) * HD + kb + quad * 8;
  }

  // prologue: iter-0 walks + B frags in registers
  int4 ga = *(const int4*)(gp);
  int4 gb = *(const int4*)(gp + 4);
  int4 ua = *(const int4*)(up);
  int4 ub = *(const int4*)(up + 4);
  short8 bgr[4], bur[4];
  #pragma unroll
  for (int t = 0; t < 4; ++t) {
    bgr[t] = __builtin_bit_cast(short8, *(const int4*)(xgp[t]));
    bur[t] = __builtin_bit_cast(short8, *(const int4*)(xup[t]));
  }

  const f32x4 z = {0.f, 0.f, 0.f, 0.f};
  f32x4 accg[4] = {z, z, z, z};
  f32x4 accu[4] = {z, z, z, z};

  for (int k0 = 0; k0 < KC; k0 += 32) {
    // A frags: LDS LUT gather on current walks
    short8 afg, afu;
    afg[0] = (short)lutg[ga.x]; afg[1] = (short)lutg[ga.y];
    afg[2] = (short)lutg[ga.z]; afg[3] = (short)lutg[ga.w];
    afg[4] = (short)lutg[gb.x]; afg[5] = (short)lutg[gb.y];
    afg[6] = (short)lutg[gb.z]; afg[7] = (short)lutg[gb.w];
    afu[0] = (short)lutu[ua.x]; afu[1] = (short)lutu[ua.y];
    afu[2] = (short)lutu[ua.z]; afu[3] = (short)lutu[ua.w];
    afu[4] = (short)lutu[ub.x]; afu[5] = (short)lutu[ub.y];
    afu[6] = (short)lutu[ub.z]; afu[7] = (short)lutu[ub.w];

    // prefetch next-iter walks (wrap to 0 on last iter; harmless)
    const int kn = (k0 + 32 < KC) ? (k0 + 32) : 0;
    ga = *(const int4*)(gp + kn);
    gb = *(const int4*)(gp + kn + 4);
    ua = *(const int4*)(up + kn);
    ub = *(const int4*)(up + kn + 4);

    // MFMA on current B frags, then prefetch next-iter B frags
    #pragma unroll
    for (int t = 0; t < 4; ++t) {
      accg[t] = __builtin_amdgcn_mfma_f32_16x16x32_bf16(afg, bgr[t], accg[t], 0, 0, 0);
      accu[t] = __builtin_amdgcn_mfma_f32_16x16x32_bf16(afu, bur[t], accu[t], 0, 0, 0);
      bgr[t] = __builtin_bit_cast(short8, *(const int4*)(xgp[t] + kn));
      bur[t] = __builtin_bit_cast(short8, *(const int4*)(xup[t] + kn));
    }
  }

  // epilogue: D layout col=lane&15 (batch), row=quad*4+reg (i)
  const int irow = mrow0 + quad * 4;
  #pragma unroll
  for (int t = 0; t < 4; ++t) {
    const int b = t*16 + col;
    float* pgb = pg + (size_t)b * ID + irow;
    float* pub = pu + (size_t)b * ID + irow;
    #pragma unroll
    for (int r = 0; r < 4; ++r) {
      atomicAdd(pgb + r, accg[t][r]);
      atomicAdd(pub + r, accu[t][r]);
    }
  }
}

// ---------------------------------------------------------------------------
// hidden epilogue: hidden[b][i] = bf16(silu(0.02*gsl*pg) * 0.02*usl*pu * dsr)
// ---------------------------------------------------------------------------
__global__ __launch_bounds__(256) void hidden_kernel(
    const float* __restrict__ pg, const float* __restrict__ pu,
    const float* __restrict__ gsl, const float* __restrict__ usl,
    const float* __restrict__ dsr,
    unsigned short* __restrict__ hidden)
{
  const int t = blockIdx.x * 256 + threadIdx.x;   // over NB*ID/4 = 229376
  const int I4 = ID / 4;
  const int b = t / I4, i4 = t % I4;
  float4 g4 = ((const float4*)pg)[(size_t)b * I4 + i4];
  float4 u4 = ((const float4*)pu)[(size_t)b * I4 + i4];
  float4 sg = ((const float4*)gsl)[i4];
  float4 su = ((const float4*)usl)[i4];
  float4 sd = ((const float4*)dsr)[i4];
  float g0 = g4.x * 0.02f * sg.x, u0 = u4.x * 0.02f * su.x;
  float g1 = g4.y * 0.02f * sg.y, u1 = u4.y * 0.02f * su.y;
  float g2 = g4.z * 0.02f * sg.z, u2 = u4.z * 0.02f * su.z;
  float g3 = g4.w * 0.02f * sg.w, u3 = u4.w * 0.02f * su.w;
  ushort4 hv;
  hv.x = f2bf((g0 / (1.f + __expf(-g0))) * u0 * sd.x);
  hv.y = f2bf((g1 / (1.f + __expf(-g1))) * u1 * sd.y);
  hv.z = f2bf((g2 / (1.f + __expf(-g2))) * u2 * sd.z);
  hv.w = f2bf((g3 / (1.f + __expf(-g3))) * u3 * sd.w);
  ((ushort4*)hidden)[(size_t)b * I4 + i4] = hv;
}

// ---------------------------------------------------------------------------
// down: same barrier-free structure. block = 4 waves, M-strip = 64 h-rows,
// K chunk = 896, grid (64, D_KS) = (64, 16). B frags direct from hidden
// (1.75 MB, L2-resident). f32 atomicAdd into out, 0.02*dsl fused.
// ---------------------------------------------------------------------------
__global__ __launch_bounds__(256, 4) void down_kernel(
    const int* __restrict__ dw, const float* __restrict__ lutd_f,
    const unsigned short* __restrict__ hidden,
    const float* __restrict__ dsl,
    float* __restrict__ out)
{
  __shared__ unsigned short lutd[NLUTN];       // 8 KB

  const int tid = threadIdx.x;
  #pragma unroll
  for (int i = tid; i < NLUTN/4; i += 256) {
    float4 d = ((const float4*)lutd_f)[i];
    ((ushort4*)lutd)[i] = make_ushort4(f2bf(d.x), f2bf(d.y), f2bf(d.z), f2bf(d.w));
  }
  __syncthreads();   // the ONLY barrier

  const int lane = tid & 63;
  const int wv   = tid >> 6;
  const int col  = lane & 15;
  const int quad = lane >> 4;
  const int m0   = blockIdx.x * 64;            // h strip
  const int mrow0 = m0 + wv * 16;
  const int kb   = blockIdx.y * (ID / D_KS);
  const int KC   = ID / D_KS;                  // 896

  const int* dp = dw + (size_t)(mrow0 + col) * ID + kb + quad * 8;
  const unsigned short* hp[4];
  #pragma unroll
  for (int t = 0; t < 4; ++t)
    hp[t] = hidden + (size_t)(t*16 + col) * ID + kb + quad * 8;

  int4 da = *(const int4*)(dp);
  int4 db = *(const int4*)(dp + 4);
  short8 bhr[4];
  #pragma unroll
  for (int t = 0; t < 4; ++t)
    bhr[t] = __builtin_bit_cast(short8, *(const int4*)(hp[t]));

  const f32x4 z = {0.f, 0.f, 0.f, 0.f};
  f32x4 acc[4] = {z, z, z, z};

  for (int k0 = 0; k0 < KC; k0 += 32) {
    short8 af;
    af[0] = (short)lutd[da.x]; af[1] = (short)lutd[da.y];
    af[2] = (short)lutd[da.z]; af[3] = (short)lutd[da.w];
    af[4] = (short)lutd[db.x]; af[5] = (short)lutd[db.y];
    af[6] = (short)lutd[db.z]; af[7] = (short)lutd[db.w];

    const int kn = (k0 + 32 < KC) ? (k0 + 32) : 0;
    da = *(const int4*)(dp + kn);
    db = *(const int4*)(dp + kn + 4);

    #pragma unroll
    for (int t = 0; t < 4; ++t) {
      acc[t] = __builtin_amdgcn_mfma_f32_16x16x32_bf16(af, bhr[t], acc[t], 0, 0, 0);
      bhr[t] = __builtin_bit_cast(short8, *(const int4*)(hp[t] + kn));
    }
  }

  const int hrow = mrow0 + quad * 4;
  float sc[4];
  #pragma unroll
  for (int r = 0; r < 4; ++r) sc[r] = 0.02f * dsl[hrow + r];
  #pragma unroll
  for (int t = 0; t < 4; ++t) {
    const int b = t*16 + col;
    float* ob = out + (size_t)b * HD + hrow;
    #pragma unroll
    for (int r = 0; r < 4; ++r)
      atomicAdd(ob + r, acc[t][r] * sc[r]);
  }
}

// ---------------------------------------------------------------------------
extern "C" void kernel_launch(void* const* d_in, const int* in_sizes, int n_in,
                              void* d_out, int out_size, void* d_ws, size_t ws_size,
                              hipStream_t stream) {
  const float* x    = (const float*)d_in[0];
  const float* lutg = (const float*)d_in[1];
  const float* lutu = (const float*)d_in[2];
  const float* lutd = (const float*)d_in[3];
  const int*   gw   = (const int*)d_in[4];
  const int*   uw   = (const int*)d_in[5];
  const int*   dw   = (const int*)d_in[6];
  const float* gsl  = (const float*)d_in[7];
  const float* gsr  = (const float*)d_in[8];
  const float* usl  = (const float*)d_in[9];
  const float* usr  = (const float*)d_in[10];
  const float* dsl  = (const float*)d_in[11];
  const float* dsr  = (const float*)d_in[12];
  float* out = (float*)d_out;

  // ws layout: xg (512K) | xu (512K) | hidden (1.75M) | pg (3.5M) | pu (3.5M)
  unsigned short* xg     = (unsigned short*)d_ws;
  unsigned short* xu     = xg + (size_t)NB * HD;
  unsigned short* hidden = xu + (size_t)NB * HD;
  float* pg = (float*)(hidden + (size_t)NB * ID);
  float* pu = pg + (size_t)NB * ID;

  hipMemsetAsync(d_out, 0, (size_t)NB * HD * sizeof(float), stream);
  hipMemsetAsync(pg, 0, (size_t)2 * NB * ID * sizeof(float), stream);
  prep_kernel<<<(NB*HD/4 + 255)/256, 256, 0, stream>>>(x, gsr, usr, xg, xu);
  gate_up_kernel<<<dim3(ID/64, GU_KS), 256, 0, stream>>>(gw, uw, lutg, lutu,
                                                         xg, xu, pg, pu);
  hidden_kernel<<<(NB*ID/4 + 255)/256, 256, 0, stream>>>(pg, pu, gsl, usl, dsr,
                                                         hidden);
  down_kernel<<<dim3(HD/64, D_KS), 256, 0, stream>>>(dw, lutd, hidden, dsl, out);
}